// Round 1
// baseline (1916.382 us; speedup 1.0000x reference)
//
#include <hip/hip_runtime.h>
#include <stdint.h>
#include <math.h>

// JAX PRNG semantics: 1 = jax_threefry_partitionable (default since JAX 0.4.36),
// 0 = legacy "original" counter scheme. Flip if validation shows massive idx mismatch.
#ifndef JAX_PARTITIONABLE
#define JAX_PARTITIONABLE 1
#endif

#define BG 64
#define NG 1024
#define KK 16
#define CC 128
#define NNODE (BG * NG)          // 65536
#define NSOFT (BG * NG * KK)     // 1048576
#define FEPS 1e-20f

__host__ __device__ __forceinline__ uint32_t rotl32u(uint32_t x, int r) {
  return (x << r) | (x >> (32 - r));
}

// Threefry-2x32, 20 rounds, exactly as jax/_src/prng.py
__host__ __device__ __forceinline__ void tf2x32(uint32_t k0, uint32_t k1,
                                                uint32_t x0, uint32_t x1,
                                                uint32_t &o0, uint32_t &o1) {
  uint32_t k2 = k0 ^ k1 ^ 0x1BD11BDAu;
  x0 += k0; x1 += k1;
#define TFR(r) { x0 += x1; x1 = rotl32u(x1, r); x1 ^= x0; }
  TFR(13) TFR(15) TFR(26) TFR(6)
  x0 += k1; x1 += k2 + 1u;
  TFR(17) TFR(29) TFR(16) TFR(24)
  x0 += k2; x1 += k0 + 2u;
  TFR(13) TFR(15) TFR(26) TFR(6)
  x0 += k0; x1 += k1 + 3u;
  TFR(17) TFR(29) TFR(16) TFR(24)
  x0 += k1; x1 += k2 + 4u;
  TFR(13) TFR(15) TFR(26) TFR(6)
  x0 += k2; x1 += k0 + 5u;
#undef TFR
  o0 = x0; o1 = x1;
}

// jax.random.uniform element m of a flat array of even size (half = size/2)
__device__ __forceinline__ float jax_uniform01(uint32_t ka, uint32_t kb,
                                               uint32_t m, uint32_t half) {
#if JAX_PARTITIONABLE
  uint32_t o0, o1;
  tf2x32(ka, kb, 0u, m, o0, o1);          // 64-bit counter: hi=0, lo=m
  uint32_t bits = o0 ^ o1;
#else
  uint32_t pi = (m < half) ? m : (m - half);
  uint32_t o0, o1;
  tf2x32(ka, kb, pi, pi + half, o0, o1);  // pair (i, half+i)
  uint32_t bits = (m < half) ? o0 : o1;
#endif
  float f = __uint_as_float((bits >> 9) | 0x3f800000u) - 1.0f;
  return fmaxf(f, 0.0f);
}

// Exact jax.lax.top_k semantics: descending value, ties -> smaller index first.
// Iterating i ascending + strict '>' insertion gives the stable order.
// Fully unrolled, compile-time indices only (keeps tv/ti in VGPRs).
__device__ __forceinline__ void topk_insert(float (&tv)[16], int (&ti)[16],
                                            float v, int i) {
  if (v > tv[15]) {
    #pragma unroll
    for (int p = 15; p >= 1; --p) {
      bool c1 = v > tv[p - 1];
      bool c2 = v > tv[p];
      tv[p] = c1 ? tv[p - 1] : (c2 ? v : tv[p]);
      ti[p] = c1 ? ti[p - 1] : (c2 ? i : ti[p]);
    }
    if (v > tv[0]) { tv[0] = v; ti[0] = i; }
  }
}

// ---- h = x @ W1 + b1 ------------------------------------------------------
__global__ __launch_bounds__(128) void k_gemm1(const float* __restrict__ x,
                                               const float* __restrict__ W1,
                                               const float* __restrict__ b1,
                                               float* __restrict__ h) {
  const int row = blockIdx.x;
  const int c = threadIdx.x;
  __shared__ float xs[CC];
  xs[c] = x[(size_t)row * CC + c];
  __syncthreads();
  float acc = 0.f;
  #pragma unroll 8
  for (int k = 0; k < CC; ++k) acc = fmaf(xs[k], W1[(size_t)k * CC + c], acc);
  h[(size_t)row * CC + c] = acc + b1[c];
}

// ---- batchnorm stats (deterministic tree reductions, no atomics) ----------
__global__ __launch_bounds__(256) void k_bn_mu(const float* __restrict__ h,
                                               float* __restrict__ mu) {
  const int c = blockIdx.x, t = threadIdx.x;
  float s = 0.f;
  for (int r = t; r < NNODE; r += 256) s += h[(size_t)r * CC + c];
  __shared__ float red[256];
  red[t] = s; __syncthreads();
  for (int o = 128; o > 0; o >>= 1) {
    if (t < o) red[t] += red[t + o];
    __syncthreads();
  }
  if (t == 0) mu[c] = red[0] * (1.0f / NNODE);   // /2^16 exact
}

__global__ __launch_bounds__(256) void k_bn_var(const float* __restrict__ h,
                                                const float* __restrict__ mu,
                                                float* __restrict__ sq) {
  const int c = blockIdx.x, t = threadIdx.x;
  const float m = mu[c];
  float s = 0.f;
  for (int r = t; r < NNODE; r += 256) {
    float d = h[(size_t)r * CC + c] - m;
    s = fmaf(d, d, s);
  }
  __shared__ float red[256];
  red[t] = s; __syncthreads();
  for (int o = 128; o > 0; o >>= 1) {
    if (t < o) red[t] += red[t + o];
    __syncthreads();
  }
  if (t == 0) sq[c] = sqrtf(red[0] * (1.0f / NNODE) + 1e-5f);
}

// ---- normalize + relu + @W2 + b2 + 0.001*uniform(k1) ----------------------
__global__ __launch_bounds__(128) void k_emb(const float* __restrict__ h,
                                             const float* __restrict__ mu,
                                             const float* __restrict__ sq,
                                             const float* __restrict__ gamma,
                                             const float* __restrict__ beta,
                                             const float* __restrict__ W2,
                                             const float* __restrict__ b2,
                                             float* __restrict__ e,
                                             uint32_t ka, uint32_t kb) {
  const int row = blockIdx.x, t = threadIdx.x;
  __shared__ float hn[CC];
  float v = (h[(size_t)row * CC + t] - mu[t]) / sq[t] * gamma[t] + beta[t];
  hn[t] = fmaxf(v, 0.f);
  __syncthreads();
  if (t < 10) {
    float acc = 0.f;
    #pragma unroll
    for (int k = 0; k < CC; ++k) acc = fmaf(hn[k], W2[(size_t)k * 10 + t], acc);
    acc += b2[t];
    uint32_t m = (uint32_t)row * 10u + (uint32_t)t;  // (B*N,10) flat, size 655360
    float u = jax_uniform01(ka, kb, m, 327680u);
    e[(size_t)row * 10 + t] = acc + u * 0.001f;
  }
}

// ---- soft edges: per-target gumbel top-16 over 1024 sources ---------------
__global__ __launch_bounds__(64) void k_soft(const float* __restrict__ e,
                                             const float* __restrict__ tsc,
                                             float* __restrict__ out,
                                             uint32_t ka, uint32_t kb) {
  const int lane = threadIdx.x;
  const int b = blockIdx.x >> 4;
  const int jt = ((blockIdx.x & 15) << 6) + lane;   // target column
  const float negt = -tsc[0];
  const float* eg = e + (size_t)b * NG * 10;
  __shared__ __align__(16) float ch[64 * 12];       // pad 10->12 for b128 reads

  float ej[10];
  #pragma unroll
  for (int d = 0; d < 10; ++d) ej[d] = eg[(size_t)jt * 10 + d];

  float tv[16]; int ti[16];
  #pragma unroll
  for (int q = 0; q < 16; ++q) { tv[q] = -INFINITY; ti[q] = 0; }

  for (int ci = 0; ci < 16; ++ci) {
    __syncthreads();
    {
      const float* rp = eg + (size_t)(ci * 64 + lane) * 10;
      #pragma unroll
      for (int d = 0; d < 10; ++d) ch[lane * 12 + d] = rp[d];
    }
    __syncthreads();
    // u[b,i,jt]: flat m = b*2^20 + i*2^10 + jt   (size 2^26, half 2^25)
    uint32_t m = ((uint32_t)b << 20) + ((uint32_t)(ci * 64) << 10) + (uint32_t)jt;
    #pragma unroll 2
    for (int s = 0; s < 64; ++s, m += (uint32_t)NG) {
      const float4* c4 = (const float4*)&ch[s * 12];
      float4 ea = c4[0], eb = c4[1], ec = c4[2];   // broadcast ds_read_b128 x3
      float dd, acc;
      dd = ej[0] - ea.x; acc = dd * dd;
      dd = ej[1] - ea.y; acc = fmaf(dd, dd, acc);
      dd = ej[2] - ea.z; acc = fmaf(dd, dd, acc);
      dd = ej[3] - ea.w; acc = fmaf(dd, dd, acc);
      dd = ej[4] - eb.x; acc = fmaf(dd, dd, acc);
      dd = ej[5] - eb.y; acc = fmaf(dd, dd, acc);
      dd = ej[6] - eb.z; acc = fmaf(dd, dd, acc);
      dd = ej[7] - eb.w; acc = fmaf(dd, dd, acc);
      dd = ej[8] - ec.x; acc = fmaf(dd, dd, acc);
      dd = ej[9] - ec.y; acc = fmaf(dd, dd, acc);
      float dist = sqrtf(acc);          // linalg.norm ...
      float d2 = dist * dist;           // ... then dist**2 (match ref rounding)
      float p = expf(negt * d2);
      float u = jax_uniform01(ka, kb, m, 1u << 25);
      float li = logf(u + FEPS);
      float g = -logf(-li + FEPS);      // gumbel
      float v = logf(p + FEPS) + g;
      topk_insert(tv, ti, v, ci * 64 + s);
    }
  }

  // vals = softmax(top16); vals /= vals.max()  (literal op order)
  float uex[16]; float ssum = 0.f;
  float m0 = tv[0];
  #pragma unroll
  for (int q = 0; q < 16; ++q) { uex[q] = expf(tv[q] - m0); ssum += uex[q]; }
  float s0 = uex[0] / ssum;
  const int node = b * NG + jt;
  size_t base = (size_t)node * KK;
  float tgtf = (float)node;
  #pragma unroll
  for (int q = 0; q < 16; ++q) {
    float sv = uex[q] / ssum;
    float srcf = (float)(b * NG + ti[q]);
    out[base + q] = sv / s0;                               // vals
    out[(size_t)NSOFT + base + q] = srcf;                  // soft_idx row0
    out[2 * (size_t)NSOFT + base + q] = tgtf;              // soft_idx row1
    out[3 * (size_t)NSOFT + base + q] = srcf;              // edge_index row0 (soft part)
    out[5 * (size_t)NSOFT + base + q] = tgtf;              // edge_index row1 (soft part)
  }
}

// ---- knn edges: per-node nearest-16 over 3-d positions --------------------
__global__ __launch_bounds__(64) void k_knn(const float* __restrict__ pos,
                                            float* __restrict__ out) {
  const int lane = threadIdx.x;
  const int b = blockIdx.x >> 4;
  const int it = ((blockIdx.x & 15) << 6) + lane;
  const float* pg = pos + (size_t)b * NG * 3;
  __shared__ __align__(16) float ch[64 * 4];
  float px = pg[(size_t)it * 3 + 0];
  float py = pg[(size_t)it * 3 + 1];
  float pz = pg[(size_t)it * 3 + 2];

  float tv[16]; int ti[16];
  #pragma unroll
  for (int q = 0; q < 16; ++q) { tv[q] = -INFINITY; ti[q] = 0; }

  for (int ci = 0; ci < 16; ++ci) {
    __syncthreads();
    {
      const float* rp = pg + (size_t)(ci * 64 + lane) * 3;
      ch[lane * 4 + 0] = rp[0];
      ch[lane * 4 + 1] = rp[1];
      ch[lane * 4 + 2] = rp[2];
    }
    __syncthreads();
    #pragma unroll 4
    for (int s = 0; s < 64; ++s) {
      int j = ci * 64 + s;
      const float4 q = *(const float4*)&ch[s * 4];
      float dx = px - q.x, dy = py - q.y, dz = pz - q.z;
      float d2 = dx * dx;
      d2 += dy * dy;
      d2 += dz * dz;
      if (j == it) d2 += 1e10f;        // eye * 1e10 (exclude self)
      topk_insert(tv, ti, -d2, j);     // top_k(-d2)
    }
  }
  const int node = b * NG + it;
  size_t base = (size_t)node * KK;
  float tgtf = (float)node;
  #pragma unroll
  for (int q = 0; q < 16; ++q) {
    out[4 * (size_t)NSOFT + base + q] = (float)(b * NG + ti[q]);  // edge row0 (knn)
    out[6 * (size_t)NSOFT + base + q] = tgtf;                     // edge row1 (knn)
  }
}

extern "C" void kernel_launch(void* const* d_in, const int* in_sizes, int n_in,
                              void* d_out, int out_size, void* d_ws, size_t ws_size,
                              hipStream_t stream) {
  const float* x     = (const float*)d_in[0];
  const float* pos   = (const float*)d_in[1];
  const float* W1    = (const float*)d_in[2];
  const float* b1    = (const float*)d_in[3];
  const float* gamma = (const float*)d_in[4];
  const float* beta  = (const float*)d_in[5];
  const float* W2    = (const float*)d_in[6];
  const float* b2    = (const float*)d_in[7];
  const float* t     = (const float*)d_in[8];
  float* out = (float*)d_out;

  float* ws = (float*)d_ws;
  float* h  = ws;                               // 65536*128
  float* e  = h + (size_t)NNODE * CC;           // 65536*10
  float* mu = e + (size_t)NNODE * 10;           // 128
  float* sq = mu + CC;                          // 128

  // key(42) = (0,42); split -> k1, k2
  uint32_t k1a, k1b, k2a, k2b;
#if JAX_PARTITIONABLE
  tf2x32(0u, 42u, 0u, 0u, k1a, k1b);
  tf2x32(0u, 42u, 0u, 1u, k2a, k2b);
#else
  uint32_t a0, a1, c0, c1;
  tf2x32(0u, 42u, 0u, 2u, a0, a1);   // pairs (0,2),(1,3): k1=(a0,c0), k2=(a1,c1)
  tf2x32(0u, 42u, 1u, 3u, c0, c1);
  k1a = a0; k1b = c0; k2a = a1; k2b = c1;
#endif

  k_gemm1<<<dim3(NNODE), dim3(CC), 0, stream>>>(x, W1, b1, h);
  k_bn_mu<<<dim3(CC), dim3(256), 0, stream>>>(h, mu);
  k_bn_var<<<dim3(CC), dim3(256), 0, stream>>>(h, mu, sq);
  k_emb<<<dim3(NNODE), dim3(CC), 0, stream>>>(h, mu, sq, gamma, beta, W2, b2, e, k1a, k1b);
  k_knn<<<dim3(1024), dim3(64), 0, stream>>>(pos, out);
  k_soft<<<dim3(1024), dim3(64), 0, stream>>>(e, t, out, k2a, k2b);
}

// Round 2
// 862.734 us; speedup vs baseline: 2.2213x; 2.2213x over previous
//
#include <hip/hip_runtime.h>
#include <stdint.h>
#include <math.h>

#define BG 64
#define NG 1024
#define KK 16
#define CC 128
#define NNODE (BG * NG)          // 65536
#define NSOFT (BG * NG * KK)     // 1048576
#define FEPS 1e-20f

__host__ __device__ __forceinline__ uint32_t rotl32u(uint32_t x, int r) {
  return (x << r) | (x >> (32 - r));
}

// Threefry-2x32, 20 rounds, exactly as jax/_src/prng.py (partitionable mode)
__host__ __device__ __forceinline__ void tf2x32(uint32_t k0, uint32_t k1,
                                                uint32_t x0, uint32_t x1,
                                                uint32_t &o0, uint32_t &o1) {
  uint32_t k2 = k0 ^ k1 ^ 0x1BD11BDAu;
  x0 += k0; x1 += k1;
#define TFR(r) { x0 += x1; x1 = rotl32u(x1, r); x1 ^= x0; }
  TFR(13) TFR(15) TFR(26) TFR(6)
  x0 += k1; x1 += k2 + 1u;
  TFR(17) TFR(29) TFR(16) TFR(24)
  x0 += k2; x1 += k0 + 2u;
  TFR(13) TFR(15) TFR(26) TFR(6)
  x0 += k0; x1 += k1 + 3u;
  TFR(17) TFR(29) TFR(16) TFR(24)
  x0 += k1; x1 += k2 + 4u;
  TFR(13) TFR(15) TFR(26) TFR(6)
  x0 += k2; x1 += k0 + 5u;
#undef TFR
  o0 = x0; o1 = x1;
}

// jax.random.uniform element m (threefry_partitionable: counter hi=0, lo=m)
__device__ __forceinline__ float jax_uniform01(uint32_t ka, uint32_t kb, uint32_t m) {
  uint32_t o0, o1;
  tf2x32(ka, kb, 0u, m, o0, o1);
  uint32_t bits = o0 ^ o1;
  float f = __uint_as_float((bits >> 9) | 0x3f800000u) - 1.0f;
  return fmaxf(f, 0.0f);
}

// jax.lax.top_k semantics: descending value; insertion order = ascending index
// gives ties -> smaller index. Fully unrolled, compile-time indices only.
__device__ __forceinline__ void topk_insert(float (&tv)[16], int (&ti)[16],
                                            float v, int i) {
  if (v > tv[15]) {
    #pragma unroll
    for (int p = 15; p >= 1; --p) {
      bool c1 = v > tv[p - 1];
      bool c2 = v > tv[p];
      tv[p] = c1 ? tv[p - 1] : (c2 ? v : tv[p]);
      ti[p] = c1 ? ti[p - 1] : (c2 ? i : ti[p]);
    }
    if (v > tv[0]) { tv[0] = v; ti[0] = i; }
  }
}

// ---- h = x @ W1 + b1 : 16 rows x 128 cols per 256-thread block ------------
__global__ __launch_bounds__(256) void k_gemm1(const float* __restrict__ x,
                                               const float* __restrict__ W1,
                                               const float* __restrict__ b1,
                                               float* __restrict__ h) {
  __shared__ __align__(16) float xs[16 * 128];
  const int t = threadIdx.x;
  const size_t blockBase = (size_t)blockIdx.x * (16 * 128);
  #pragma unroll
  for (int j = 0; j < 8; ++j) xs[t + j * 256] = x[blockBase + t + j * 256];
  __syncthreads();
  const int c = t & 127;
  const int rg = t >> 7;                     // 0/1 -> rows rg*8..rg*8+7
  float acc[8];
  #pragma unroll
  for (int j = 0; j < 8; ++j) acc[j] = 0.f;
  const float* xrow = &xs[rg * 8 * 128];
  for (int k4 = 0; k4 < 128; k4 += 4) {
    const float w0 = W1[(size_t)(k4 + 0) * 128 + c];
    const float w1 = W1[(size_t)(k4 + 1) * 128 + c];
    const float w2 = W1[(size_t)(k4 + 2) * 128 + c];
    const float w3 = W1[(size_t)(k4 + 3) * 128 + c];
    #pragma unroll
    for (int j = 0; j < 8; ++j) {
      const float4 xv = *(const float4*)&xrow[j * 128 + k4];
      acc[j] = fmaf(xv.x, w0, acc[j]);
      acc[j] = fmaf(xv.y, w1, acc[j]);
      acc[j] = fmaf(xv.z, w2, acc[j]);
      acc[j] = fmaf(xv.w, w3, acc[j]);
    }
  }
  const float bb = b1[c];
  #pragma unroll
  for (int j = 0; j < 8; ++j)
    h[blockBase + (size_t)(rg * 8 + j) * 128 + c] = acc[j] + bb;
}

// ---- BN stats one pass: per-block partial (sum, sumsq) per column ---------
__global__ __launch_bounds__(256) void k_bn_part(const float* __restrict__ h,
                                                 float* __restrict__ p1,
                                                 float* __restrict__ p2) {
  const int t = threadIdx.x;
  const int cg = t & 31;                     // 4-column group
  const int rg = t >> 5;                     // 0..7
  const size_t rowBase = (size_t)blockIdx.x * 256;
  float s1[4] = {0, 0, 0, 0}, s2[4] = {0, 0, 0, 0};
  for (int i = 0; i < 32; ++i) {
    const size_t r = rowBase + (size_t)i * 8 + rg;
    const float4 v = *(const float4*)&h[r * 128 + cg * 4];
    s1[0] += v.x; s2[0] = fmaf(v.x, v.x, s2[0]);
    s1[1] += v.y; s2[1] = fmaf(v.y, v.y, s2[1]);
    s1[2] += v.z; s2[2] = fmaf(v.z, v.z, s2[2]);
    s1[3] += v.w; s2[3] = fmaf(v.w, v.w, s2[3]);
  }
  __shared__ float red1[8 * 128];
  __shared__ float red2[8 * 128];
  #pragma unroll
  for (int i = 0; i < 4; ++i) {
    red1[rg * 128 + cg * 4 + i] = s1[i];
    red2[rg * 128 + cg * 4 + i] = s2[i];
  }
  __syncthreads();
  if (t < 128) {
    float a = 0.f;
    #pragma unroll
    for (int g = 0; g < 8; ++g) a += red1[g * 128 + t];
    p1[(size_t)blockIdx.x * 128 + t] = a;
  } else {
    const int c = t - 128;
    float a = 0.f;
    #pragma unroll
    for (int g = 0; g < 8; ++g) a += red2[g * 128 + c];
    p2[(size_t)blockIdx.x * 128 + c] = a;
  }
}

__global__ __launch_bounds__(128) void k_bn_final(const float* __restrict__ p1,
                                                  const float* __restrict__ p2,
                                                  const float* __restrict__ gamma,
                                                  const float* __restrict__ beta,
                                                  float* __restrict__ scale,
                                                  float* __restrict__ shift) {
  const int c = threadIdx.x;
  float s1 = 0.f, s2 = 0.f;
  for (int b = 0; b < 256; ++b) {
    s1 += p1[b * 128 + c];
    s2 += p2[b * 128 + c];
  }
  const float mu = s1 * (1.0f / NNODE);
  float var = s2 * (1.0f / NNODE) - mu * mu;   // mu ~ 0 -> no cancellation
  var = fmaxf(var, 0.f);
  const float sc = gamma[c] / sqrtf(var + 1e-5f);
  scale[c] = sc;
  shift[c] = beta[c] - mu * sc;
}

// ---- normalize+relu (fma) + @W2 + b2 + 0.001*uniform(k1): 64 rows/block ---
__global__ __launch_bounds__(256) void k_emb(const float* __restrict__ h,
                                             const float* __restrict__ scale,
                                             const float* __restrict__ shift,
                                             const float* __restrict__ W2,
                                             const float* __restrict__ b2,
                                             float* __restrict__ e,
                                             uint32_t ka, uint32_t kb) {
  __shared__ __align__(16) float hn[64 * 132];   // pitch 132: 16B-aligned rows
  const int t = threadIdx.x;
  const int rowBase = blockIdx.x * 64;
  {
    const int c = t & 127;
    const float sc = scale[c], sh = shift[c];
    #pragma unroll
    for (int j = 0; j < 32; ++j) {
      const int r = (t >> 7) + j * 2;
      const float v = fmaf(h[(size_t)(rowBase + r) * 128 + c], sc, sh);
      hn[r * 132 + c] = fmaxf(v, 0.f);
    }
  }
  __syncthreads();
  #pragma unroll
  for (int j = 0; j < 3; ++j) {
    const int o = t + j * 256;
    if (o < 640) {
      const int r = o / 10;
      const int col = o - r * 10;
      float acc = 0.f;
      for (int k4 = 0; k4 < 128; k4 += 4) {
        const float4 hv = *(const float4*)&hn[r * 132 + k4];
        acc = fmaf(hv.x, W2[(k4 + 0) * 10 + col], acc);
        acc = fmaf(hv.y, W2[(k4 + 1) * 10 + col], acc);
        acc = fmaf(hv.z, W2[(k4 + 2) * 10 + col], acc);
        acc = fmaf(hv.w, W2[(k4 + 3) * 10 + col], acc);
      }
      acc += b2[col];
      const uint32_t m = (uint32_t)(rowBase + r) * 10u + (uint32_t)col;
      const float u = jax_uniform01(ka, kb, m);
      e[(size_t)(rowBase + r) * 10 + col] = acc + u * 0.001f;
    }
  }
}

// ---- soft edges: 8 waves/block, each scans 128 strided sources + merge ----
__global__ __launch_bounds__(512) void k_soft(const float* __restrict__ e,
                                              const float* __restrict__ tsc,
                                              float* __restrict__ out,
                                              uint32_t ka, uint32_t kb) {
  // union: stage double-buffer 2*768 floats  |  merge mv 4352 f + mi 4352 i
  __shared__ __align__(16) float smem[8704];
  float* stage = smem;
  float* mv = smem;
  int*   mi = (int*)(smem + 4352);

  const int t = threadIdx.x;
  const int lane = t & 63;
  const int w = t >> 6;
  const int b = blockIdx.x >> 4;
  const int jt = ((blockIdx.x & 15) << 6) + lane;   // target column
  const float negt = -tsc[0];
  const float* eg = e + (size_t)b * (NG * 10);

  float ej[10];
  #pragma unroll
  for (int d = 0; d < 10; ++d) ej[d] = eg[(size_t)jt * 10 + d];

  float tv[16]; int ti[16];
  #pragma unroll
  for (int q = 0; q < 16; ++q) { tv[q] = -INFINITY; ti[q] = 0; }

  const uint32_t mBase = ((uint32_t)b << 20) + (uint32_t)jt;

  for (int ci = 0; ci < 16; ++ci) {
    float* buf = stage + (ci & 1) * 768;
    {   // stage 64 source rows (640 floats), pitch 12 for aligned float4
      const int r0 = t / 10, d0 = t - r0 * 10;
      buf[r0 * 12 + d0] = eg[(size_t)ci * 640 + t];
      if (t < 128) {
        const int f1 = t + 512;
        const int r1 = f1 / 10, d1 = f1 - r1 * 10;
        buf[r1 * 12 + d1] = eg[(size_t)ci * 640 + f1];
      }
    }
    __syncthreads();
    #pragma unroll 2
    for (int k = 0; k < 8; ++k) {
      const int sl = w + (k << 3);               // wave-strided source
      const int s = (ci << 6) + sl;
      const float4 ea = *(const float4*)&buf[sl * 12 + 0];
      const float4 eb = *(const float4*)&buf[sl * 12 + 4];
      const float2 ec = *(const float2*)&buf[sl * 12 + 8];
      float dd, acc;
      dd = ej[0] - ea.x; acc = dd * dd;
      dd = ej[1] - ea.y; acc = fmaf(dd, dd, acc);
      dd = ej[2] - ea.z; acc = fmaf(dd, dd, acc);
      dd = ej[3] - ea.w; acc = fmaf(dd, dd, acc);
      dd = ej[4] - eb.x; acc = fmaf(dd, dd, acc);
      dd = ej[5] - eb.y; acc = fmaf(dd, dd, acc);
      dd = ej[6] - eb.z; acc = fmaf(dd, dd, acc);
      dd = ej[7] - eb.w; acc = fmaf(dd, dd, acc);
      dd = ej[8] - ec.x; acc = fmaf(dd, dd, acc);
      dd = ej[9] - ec.y; acc = fmaf(dd, dd, acc);
      const float dist = sqrtf(acc);      // linalg.norm ...
      const float d2 = dist * dist;       // ... then **2 (match ref rounding)
      const float p = __expf(negt * d2);
      const uint32_t m = mBase + ((uint32_t)s << 10);
      const float u = jax_uniform01(ka, kb, m);
      const float li = __logf(u + FEPS);
      const float g = -__logf(FEPS - li);       // gumbel
      const float v = __logf(p + FEPS) + g;
      topk_insert(tv, ti, v, s);
    }
  }

  // tree-merge 8 wave-lists -> wave 0 (pitch 17 kills bank conflicts)
  for (int hi = 4; hi >= 1; hi >>= 1) {
    __syncthreads();
    if (w >= hi && w < 2 * hi) {
      const int base = ((w - hi) * 64 + lane) * 17;
      #pragma unroll
      for (int q = 0; q < 16; ++q) { mv[base + q] = tv[q]; mi[base + q] = ti[q]; }
    }
    __syncthreads();
    if (w < hi) {
      const int base = (w * 64 + lane) * 17;
      #pragma unroll
      for (int q = 0; q < 16; ++q) topk_insert(tv, ti, mv[base + q], mi[base + q]);
    }
  }

  if (w == 0) {
    float uex[16]; float ssum = 0.f;
    const float m0 = tv[0];
    #pragma unroll
    for (int q = 0; q < 16; ++q) { uex[q] = __expf(tv[q] - m0); ssum += uex[q]; }
    const float s0 = uex[0] / ssum;
    const int node = b * NG + jt;
    const size_t base = (size_t)node * KK;
    const float tgtf = (float)node;
    #pragma unroll
    for (int q = 0; q < 16; ++q) {
      const float sv = uex[q] / ssum;
      const float srcf = (float)(b * NG + ti[q]);
      out[base + q] = sv / s0;                       // vals
      out[(size_t)NSOFT + base + q] = srcf;          // soft_idx row0
      out[2 * (size_t)NSOFT + base + q] = tgtf;      // soft_idx row1
      out[3 * (size_t)NSOFT + base + q] = srcf;      // edge row0 (soft)
      out[5 * (size_t)NSOFT + base + q] = tgtf;      // edge row1 (soft)
    }
  }
}

// ---- knn edges: 8 waves/block, all 1024 positions staged once + merge -----
__global__ __launch_bounds__(512) void k_knn(const float* __restrict__ pos,
                                             float* __restrict__ out) {
  __shared__ __align__(16) float smem[8704];
  float* ps = smem;                        // 1024*4 floats (overlaps merge buf)
  float* mv = smem;
  int*   mi = (int*)(smem + 4352);

  const int t = threadIdx.x;
  const int lane = t & 63;
  const int w = t >> 6;
  const int b = blockIdx.x >> 4;
  const int it = ((blockIdx.x & 15) << 6) + lane;
  const float* pg = pos + (size_t)b * (NG * 3);

  for (int f = t; f < 3072; f += 512) {
    const int r = f / 3, d = f - r * 3;
    ps[r * 4 + d] = pg[f];
  }
  __syncthreads();

  const float px = ps[it * 4 + 0];
  const float py = ps[it * 4 + 1];
  const float pz = ps[it * 4 + 2];

  float tv[16]; int ti[16];
  #pragma unroll
  for (int q = 0; q < 16; ++q) { tv[q] = -INFINITY; ti[q] = 0; }

  #pragma unroll 4
  for (int k = 0; k < 128; ++k) {
    const int s = w + (k << 3);
    const float4 q4 = *(const float4*)&ps[s * 4];
    const float dx = px - q4.x, dy = py - q4.y, dz = pz - q4.z;
    float d2 = dx * dx;
    d2 = fmaf(dy, dy, d2);
    d2 = fmaf(dz, dz, d2);
    if (s == it) d2 += 1e10f;              // exclude self
    topk_insert(tv, ti, -d2, s);           // top_k(-d2)
  }

  for (int hi = 4; hi >= 1; hi >>= 1) {
    __syncthreads();
    if (w >= hi && w < 2 * hi) {
      const int base = ((w - hi) * 64 + lane) * 17;
      #pragma unroll
      for (int q = 0; q < 16; ++q) { mv[base + q] = tv[q]; mi[base + q] = ti[q]; }
    }
    __syncthreads();
    if (w < hi) {
      const int base = (w * 64 + lane) * 17;
      #pragma unroll
      for (int q = 0; q < 16; ++q) topk_insert(tv, ti, mv[base + q], mi[base + q]);
    }
  }

  if (w == 0) {
    const int node = b * NG + it;
    const size_t base = (size_t)node * KK;
    const float tgtf = (float)node;
    #pragma unroll
    for (int q = 0; q < 16; ++q) {
      out[4 * (size_t)NSOFT + base + q] = (float)(b * NG + ti[q]);  // edge row0 (knn)
      out[6 * (size_t)NSOFT + base + q] = tgtf;                     // edge row1 (knn)
    }
  }
}

extern "C" void kernel_launch(void* const* d_in, const int* in_sizes, int n_in,
                              void* d_out, int out_size, void* d_ws, size_t ws_size,
                              hipStream_t stream) {
  const float* x     = (const float*)d_in[0];
  const float* pos   = (const float*)d_in[1];
  const float* W1    = (const float*)d_in[2];
  const float* b1    = (const float*)d_in[3];
  const float* gamma = (const float*)d_in[4];
  const float* beta  = (const float*)d_in[5];
  const float* W2    = (const float*)d_in[6];
  const float* b2    = (const float*)d_in[7];
  const float* t     = (const float*)d_in[8];
  float* out = (float*)d_out;

  float* ws    = (float*)d_ws;
  float* h     = ws;                              // 65536*128
  float* e     = h + (size_t)NNODE * CC;          // 65536*10
  float* p1    = e + (size_t)NNODE * 10;          // 256*128
  float* p2    = p1 + 256 * 128;                  // 256*128
  float* scale = p2 + 256 * 128;                  // 128
  float* shift = scale + CC;                      // 128

  // key(42) = (0,42); partitionable split -> k1, k2
  uint32_t k1a, k1b, k2a, k2b;
  tf2x32(0u, 42u, 0u, 0u, k1a, k1b);
  tf2x32(0u, 42u, 0u, 1u, k2a, k2b);

  k_gemm1<<<dim3(NNODE / 16), dim3(256), 0, stream>>>(x, W1, b1, h);
  k_bn_part<<<dim3(256), dim3(256), 0, stream>>>(h, p1, p2);
  k_bn_final<<<dim3(1), dim3(128), 0, stream>>>(p1, p2, gamma, beta, scale, shift);
  k_emb<<<dim3(NNODE / 64), dim3(256), 0, stream>>>(h, scale, shift, W2, b2, e, k1a, k1b);
  k_knn<<<dim3(1024), dim3(512), 0, stream>>>(pos, out);
  k_soft<<<dim3(1024), dim3(512), 0, stream>>>(e, t, out, k2a, k2b);
}

// Round 3
// 447.705 us; speedup vs baseline: 4.2805x; 1.9270x over previous
//
#include <hip/hip_runtime.h>
#include <stdint.h>
#include <math.h>

#define BG 64
#define NG 1024
#define KK 16
#define CC 128
#define NNODE (BG * NG)          // 65536
#define NSOFT (BG * NG * KK)     // 1048576
#define FEPS 1e-20f

__host__ __device__ __forceinline__ uint32_t rotl32u(uint32_t x, int r) {
  return (x << r) | (x >> (32 - r));
}

// Threefry-2x32, 20 rounds, exactly as jax/_src/prng.py (partitionable mode)
__host__ __device__ __forceinline__ void tf2x32(uint32_t k0, uint32_t k1,
                                                uint32_t x0, uint32_t x1,
                                                uint32_t &o0, uint32_t &o1) {
  uint32_t k2 = k0 ^ k1 ^ 0x1BD11BDAu;
  x0 += k0; x1 += k1;
#define TFR(r) { x0 += x1; x1 = rotl32u(x1, r); x1 ^= x0; }
  TFR(13) TFR(15) TFR(26) TFR(6)
  x0 += k1; x1 += k2 + 1u;
  TFR(17) TFR(29) TFR(16) TFR(24)
  x0 += k2; x1 += k0 + 2u;
  TFR(13) TFR(15) TFR(26) TFR(6)
  x0 += k0; x1 += k1 + 3u;
  TFR(17) TFR(29) TFR(16) TFR(24)
  x0 += k1; x1 += k2 + 4u;
  TFR(13) TFR(15) TFR(26) TFR(6)
  x0 += k2; x1 += k0 + 5u;
#undef TFR
  o0 = x0; o1 = x1;
}

// jax.random.uniform element m (threefry_partitionable: counter hi=0, lo=m)
__device__ __forceinline__ float jax_uniform01(uint32_t ka, uint32_t kb, uint32_t m) {
  uint32_t o0, o1;
  tf2x32(ka, kb, 0u, m, o0, o1);
  uint32_t bits = o0 ^ o1;
  float f = __uint_as_float((bits >> 9) | 0x3f800000u) - 1.0f;
  return fmaxf(f, 0.0f);
}

// Linear-quantized bin; identical computation in histogram and collect phases.
// Soft logits: v in [-49.9, 16.7]  -> LO=-50, span 67
__device__ __forceinline__ int vbin_soft(float v) {
  float fb = (v + 50.0f) * (256.0f / 67.0f);
  fb = fminf(fmaxf(fb, 0.0f), 255.0f);
  return (int)fb;
}
// KNN scores: v = -d2 in [-inf, 0] -> LO=-64, span 64 (d2>64 clamps to bin 0)
__device__ __forceinline__ int vbin_knn(float v) {
  float fb = (v + 64.0f) * 4.0f;
  fb = fminf(fmaxf(fb, 0.0f), 255.0f);
  return (int)fb;
}

#define LDS_WAIT() asm volatile("s_waitcnt lgkmcnt(0)" ::: "memory")

// ---- h = x @ W1 + b1 : 64 rows x 128 cols per 256-thread block ------------
__global__ __launch_bounds__(256) void k_gemm1(const float* __restrict__ x,
                                               const float* __restrict__ W1,
                                               const float* __restrict__ b1,
                                               float* __restrict__ h) {
  __shared__ __align__(16) float xs[64 * 128];   // 32 KB
  const int t = threadIdx.x;
  const size_t blockBase = (size_t)blockIdx.x * (64 * 128);
  #pragma unroll
  for (int j = 0; j < 32; ++j) xs[t + j * 256] = x[blockBase + t + j * 256];
  __syncthreads();
  const int c = t & 127;
  const int rg = t >> 7;                     // 0/1 -> rows rg*32..rg*32+31
  float acc[32];
  #pragma unroll
  for (int j = 0; j < 32; ++j) acc[j] = 0.f;
  const float* xrow = &xs[rg * 32 * 128];
  for (int k4 = 0; k4 < 128; k4 += 4) {
    const float w0 = W1[(size_t)(k4 + 0) * 128 + c];
    const float w1 = W1[(size_t)(k4 + 1) * 128 + c];
    const float w2 = W1[(size_t)(k4 + 2) * 128 + c];
    const float w3 = W1[(size_t)(k4 + 3) * 128 + c];
    #pragma unroll
    for (int j = 0; j < 32; ++j) {
      const float4 xv = *(const float4*)&xrow[j * 128 + k4];
      acc[j] = fmaf(xv.x, w0, acc[j]);
      acc[j] = fmaf(xv.y, w1, acc[j]);
      acc[j] = fmaf(xv.z, w2, acc[j]);
      acc[j] = fmaf(xv.w, w3, acc[j]);
    }
  }
  const float bb = b1[c];
  #pragma unroll
  for (int j = 0; j < 32; ++j)
    h[blockBase + (size_t)(rg * 32 + j) * 128 + c] = acc[j] + bb;
}

// ---- BN stats one pass: per-block partial (sum, sumsq) per column ---------
__global__ __launch_bounds__(256) void k_bn_part(const float* __restrict__ h,
                                                 float* __restrict__ p1,
                                                 float* __restrict__ p2) {
  const int t = threadIdx.x;
  const int cg = t & 31;
  const int rg = t >> 5;
  const size_t rowBase = (size_t)blockIdx.x * 256;
  float s1[4] = {0, 0, 0, 0}, s2[4] = {0, 0, 0, 0};
  for (int i = 0; i < 32; ++i) {
    const size_t r = rowBase + (size_t)i * 8 + rg;
    const float4 v = *(const float4*)&h[r * 128 + cg * 4];
    s1[0] += v.x; s2[0] = fmaf(v.x, v.x, s2[0]);
    s1[1] += v.y; s2[1] = fmaf(v.y, v.y, s2[1]);
    s1[2] += v.z; s2[2] = fmaf(v.z, v.z, s2[2]);
    s1[3] += v.w; s2[3] = fmaf(v.w, v.w, s2[3]);
  }
  __shared__ float red1[8 * 128];
  __shared__ float red2[8 * 128];
  #pragma unroll
  for (int i = 0; i < 4; ++i) {
    red1[rg * 128 + cg * 4 + i] = s1[i];
    red2[rg * 128 + cg * 4 + i] = s2[i];
  }
  __syncthreads();
  if (t < 128) {
    float a = 0.f;
    #pragma unroll
    for (int g = 0; g < 8; ++g) a += red1[g * 128 + t];
    p1[(size_t)blockIdx.x * 128 + t] = a;
  } else {
    const int c = t - 128;
    float a = 0.f;
    #pragma unroll
    for (int g = 0; g < 8; ++g) a += red2[g * 128 + c];
    p2[(size_t)blockIdx.x * 128 + c] = a;
  }
}

__global__ __launch_bounds__(128) void k_bn_final(const float* __restrict__ p1,
                                                  const float* __restrict__ p2,
                                                  const float* __restrict__ gamma,
                                                  const float* __restrict__ beta,
                                                  float* __restrict__ scale,
                                                  float* __restrict__ shift) {
  const int c = threadIdx.x;
  float s1 = 0.f, s2 = 0.f;
  for (int b = 0; b < 256; ++b) {
    s1 += p1[b * 128 + c];
    s2 += p2[b * 128 + c];
  }
  const float mu = s1 * (1.0f / NNODE);
  float var = s2 * (1.0f / NNODE) - mu * mu;
  var = fmaxf(var, 0.f);
  const float sc = gamma[c] / sqrtf(var + 1e-5f);
  scale[c] = sc;
  shift[c] = beta[c] - mu * sc;
}

// ---- normalize+relu (fma) + @W2 + b2 + 0.001*uniform(k1): 64 rows/block ---
__global__ __launch_bounds__(256) void k_emb(const float* __restrict__ h,
                                             const float* __restrict__ scale,
                                             const float* __restrict__ shift,
                                             const float* __restrict__ W2,
                                             const float* __restrict__ b2,
                                             float* __restrict__ e,
                                             uint32_t ka, uint32_t kb) {
  __shared__ __align__(16) float hn[64 * 132];
  const int t = threadIdx.x;
  const int rowBase = blockIdx.x * 64;
  {
    const int c = t & 127;
    const float sc = scale[c], sh = shift[c];
    #pragma unroll
    for (int j = 0; j < 32; ++j) {
      const int r = (t >> 7) + j * 2;
      const float v = fmaf(h[(size_t)(rowBase + r) * 128 + c], sc, sh);
      hn[r * 132 + c] = fmaxf(v, 0.f);
    }
  }
  __syncthreads();
  #pragma unroll
  for (int j = 0; j < 3; ++j) {
    const int o = t + j * 256;
    if (o < 640) {
      const int r = o / 10;
      const int col = o - r * 10;
      float acc = 0.f;
      for (int k4 = 0; k4 < 128; k4 += 4) {
        const float4 hv = *(const float4*)&hn[r * 132 + k4];
        acc = fmaf(hv.x, W2[(k4 + 0) * 10 + col], acc);
        acc = fmaf(hv.y, W2[(k4 + 1) * 10 + col], acc);
        acc = fmaf(hv.z, W2[(k4 + 2) * 10 + col], acc);
        acc = fmaf(hv.w, W2[(k4 + 3) * 10 + col], acc);
      }
      acc += b2[col];
      const uint32_t m = (uint32_t)(rowBase + r) * 10u + (uint32_t)col;
      const float u = jax_uniform01(ka, kb, m);
      e[(size_t)(rowBase + r) * 10 + col] = acc + u * 0.001f;
    }
  }
}

// ---- soft edges: one wave per target; histogram select, no barriers -------
__global__ __launch_bounds__(512) void k_soft(const float* __restrict__ e,
                                              const float* __restrict__ tsc,
                                              float* __restrict__ out,
                                              uint32_t ka, uint32_t kb) {
  __shared__ uint32_t bins[8][256];
  __shared__ float    cv[8][64];
  __shared__ int      cidx[8][64];
  __shared__ uint32_t cnt[8];
  __shared__ float    o16v[8][16];
  __shared__ int      o16i[8][16];

  const int t = threadIdx.x, lane = t & 63, w = t >> 6;
  const int node = blockIdx.x * 8 + w;
  const int b = node >> 10, jt = node & (NG - 1);
  const float negt = -tsc[0];
  const float* eg = e + (size_t)b * (NG * 10);

  // zero own wave's bins + counter (per-wave state; in-order LDS per wave)
  { uint4 z = {0, 0, 0, 0}; *(uint4*)&bins[w][lane * 4] = z; }
  if (lane == 0) cnt[w] = 0u;
  LDS_WAIT();

  float ej[10];
  #pragma unroll
  for (int d = 0; d < 10; ++d) ej[d] = eg[(size_t)jt * 10 + d];

  // phase 1: compute 16 scores into registers, histogram them
  float vv[16];
  const uint32_t mB = ((uint32_t)b << 20) + (uint32_t)jt;
  #pragma unroll
  for (int st = 0; st < 16; ++st) {
    const int s = st * 64 + lane;
    const float2* rp = (const float2*)(eg + (size_t)s * 10);  // 8B-aligned
    const float2 a0 = rp[0], a1 = rp[1], a2 = rp[2], a3 = rp[3], a4 = rp[4];
    float dd, acc;
    dd = ej[0] - a0.x; acc = dd * dd;
    dd = ej[1] - a0.y; acc = fmaf(dd, dd, acc);
    dd = ej[2] - a1.x; acc = fmaf(dd, dd, acc);
    dd = ej[3] - a1.y; acc = fmaf(dd, dd, acc);
    dd = ej[4] - a2.x; acc = fmaf(dd, dd, acc);
    dd = ej[5] - a2.y; acc = fmaf(dd, dd, acc);
    dd = ej[6] - a3.x; acc = fmaf(dd, dd, acc);
    dd = ej[7] - a3.y; acc = fmaf(dd, dd, acc);
    dd = ej[8] - a4.x; acc = fmaf(dd, dd, acc);
    dd = ej[9] - a4.y; acc = fmaf(dd, dd, acc);
    const float dist = sqrtf(acc);      // linalg.norm ...
    const float d2 = dist * dist;       // ... then **2 (match ref rounding)
    const float p = __expf(negt * d2);
    const float u = jax_uniform01(ka, kb, mB + ((uint32_t)s << 10));
    const float li = __logf(u + FEPS);
    const float g = -__logf(FEPS - li);           // gumbel
    const float v = __logf(p + FEPS) + g;
    vv[st] = v;
    atomicAdd(&bins[w][vbin_soft(v)], 1u);
  }
  LDS_WAIT();

  // phase 2: wave suffix-scan of 256 bins -> threshold bin B (= bin of v16)
  const uint4 c4 = *(const uint4*)&bins[w][lane * 4];
  const uint32_t lsum = c4.x + c4.y + c4.z + c4.w;
  uint32_t xs = lsum;
  #pragma unroll
  for (int off = 1; off < 64; off <<= 1) {
    uint32_t tt = (uint32_t)__shfl_down((int)xs, off, 64);
    if (lane + off < 64) xs += tt;
  }
  const uint32_t after = xs - lsum;               // sum of lanes > this one
  const uint32_t s3 = c4.w + after;
  const uint32_t s2 = c4.z + s3;
  const uint32_t s1 = c4.y + s2;
  const uint32_t s0 = c4.x + s1;
  int localB = -1;
  if (s3 >= 16u) localB = lane * 4 + 3;
  else if (s2 >= 16u) localB = lane * 4 + 2;
  else if (s1 >= 16u) localB = lane * 4 + 1;
  else if (s0 >= 16u) localB = lane * 4 + 0;
  const unsigned long long msk = __ballot(localB >= 0);
  const int hl = 63 - __builtin_clzll(msk);
  const int B = __shfl(localB, hl, 64);

  // phase 3: collect candidates (bin >= B); C = suffix(B) in [16, ~30]
  #pragma unroll
  for (int st = 0; st < 16; ++st) {
    if (vbin_soft(vv[st]) >= B) {
      const uint32_t pos = atomicAdd(&cnt[w], 1u);
      if (pos < 64u) { cv[w][pos] = vv[st]; cidx[w][pos] = st * 64 + lane; }
    }
  }
  LDS_WAIT();

  // phase 4: exact rank by count with (v desc, idx asc) = jax top_k order
  int C = (int)cnt[w]; if (C > 64) C = 64;
  const float mvv = (lane < C) ? cv[w][lane] : 0.f;
  const int   mii = (lane < C) ? cidx[w][lane] : 0;
  int rank = 0;
  for (int j = 0; j < C; ++j) {
    const float vj = cv[w][j];
    const int ij = cidx[w][j];
    if (vj > mvv || (vj == mvv && ij < mii)) ++rank;
  }
  if (lane < C && rank < 16) { o16v[w][rank] = mvv; o16i[w][rank] = mii; }
  LDS_WAIT();

  // phase 5: softmax / max-normalize (literal ref op order), write outputs
  if (lane < 16) {
    const float vq = o16v[w][lane];
    const float m0 = o16v[w][0];
    float uex = __expf(vq - m0);
    float ss = uex;
    #pragma unroll
    for (int off = 1; off < 16; off <<= 1) ss += __shfl_xor(ss, off, 16);
    const float u0 = __shfl(uex, 0, 16);
    const float s0v = u0 / ss;
    const float sv = uex / ss;
    const float o = sv / s0v;
    const size_t base = (size_t)node * KK + lane;
    const float tgtf = (float)node;
    const float srcf = (float)(b * NG + o16i[w][lane]);
    out[base] = o;                                  // vals
    out[(size_t)NSOFT + base] = srcf;               // soft_idx row0
    out[2 * (size_t)NSOFT + base] = tgtf;           // soft_idx row1
    out[3 * (size_t)NSOFT + base] = srcf;           // edge row0 (soft)
    out[5 * (size_t)NSOFT + base] = tgtf;           // edge row1 (soft)
  }
}

// ---- knn edges: one wave per target node; histogram select ----------------
__global__ __launch_bounds__(512) void k_knn(const float* __restrict__ pos,
                                             float* __restrict__ out) {
  __shared__ uint32_t bins[8][256];
  __shared__ float    cv[8][64];
  __shared__ int      cidx[8][64];
  __shared__ uint32_t cnt[8];
  __shared__ int      o16i[8][16];

  const int t = threadIdx.x, lane = t & 63, w = t >> 6;
  const int node = blockIdx.x * 8 + w;
  const int b = node >> 10, it = node & (NG - 1);
  const float* pg = pos + (size_t)b * (NG * 3);

  { uint4 z = {0, 0, 0, 0}; *(uint4*)&bins[w][lane * 4] = z; }
  if (lane == 0) cnt[w] = 0u;
  LDS_WAIT();

  const float px = pg[(size_t)it * 3 + 0];
  const float py = pg[(size_t)it * 3 + 1];
  const float pz = pg[(size_t)it * 3 + 2];

  float vv[16];
  #pragma unroll
  for (int st = 0; st < 16; ++st) {
    const int s = st * 64 + lane;
    const float qx = pg[(size_t)s * 3 + 0];
    const float qy = pg[(size_t)s * 3 + 1];
    const float qz = pg[(size_t)s * 3 + 2];
    const float dx = px - qx, dy = py - qy, dz = pz - qz;
    float d2 = dx * dx;
    d2 = fmaf(dy, dy, d2);
    d2 = fmaf(dz, dz, d2);
    if (s == it) d2 += 1e10f;            // exclude self
    const float v = -d2;                 // top_k(-d2)
    vv[st] = v;
    atomicAdd(&bins[w][vbin_knn(v)], 1u);
  }
  LDS_WAIT();

  const uint4 c4 = *(const uint4*)&bins[w][lane * 4];
  const uint32_t lsum = c4.x + c4.y + c4.z + c4.w;
  uint32_t xs = lsum;
  #pragma unroll
  for (int off = 1; off < 64; off <<= 1) {
    uint32_t tt = (uint32_t)__shfl_down((int)xs, off, 64);
    if (lane + off < 64) xs += tt;
  }
  const uint32_t after = xs - lsum;
  const uint32_t s3 = c4.w + after;
  const uint32_t s2 = c4.z + s3;
  const uint32_t s1 = c4.y + s2;
  const uint32_t s0 = c4.x + s1;
  int localB = -1;
  if (s3 >= 16u) localB = lane * 4 + 3;
  else if (s2 >= 16u) localB = lane * 4 + 2;
  else if (s1 >= 16u) localB = lane * 4 + 1;
  else if (s0 >= 16u) localB = lane * 4 + 0;
  const unsigned long long msk = __ballot(localB >= 0);
  const int hl = 63 - __builtin_clzll(msk);
  const int B = __shfl(localB, hl, 64);

  #pragma unroll
  for (int st = 0; st < 16; ++st) {
    if (vbin_knn(vv[st]) >= B) {
      const uint32_t pos = atomicAdd(&cnt[w], 1u);
      if (pos < 64u) { cv[w][pos] = vv[st]; cidx[w][pos] = st * 64 + lane; }
    }
  }
  LDS_WAIT();

  int C = (int)cnt[w]; if (C > 64) C = 64;
  const float mvv = (lane < C) ? cv[w][lane] : 0.f;
  const int   mii = (lane < C) ? cidx[w][lane] : 0;
  int rank = 0;
  for (int j = 0; j < C; ++j) {
    const float vj = cv[w][j];
    const int ij = cidx[w][j];
    if (vj > mvv || (vj == mvv && ij < mii)) ++rank;
  }
  if (lane < C && rank < 16) o16i[w][rank] = mii;
  LDS_WAIT();

  if (lane < 16) {
    const size_t base = (size_t)node * KK + lane;
    out[4 * (size_t)NSOFT + base] = (float)(b * NG + o16i[w][lane]);  // edge row0 (knn)
    out[6 * (size_t)NSOFT + base] = (float)node;                      // edge row1 (knn)
  }
}

extern "C" void kernel_launch(void* const* d_in, const int* in_sizes, int n_in,
                              void* d_out, int out_size, void* d_ws, size_t ws_size,
                              hipStream_t stream) {
  const float* x     = (const float*)d_in[0];
  const float* pos   = (const float*)d_in[1];
  const float* W1    = (const float*)d_in[2];
  const float* b1    = (const float*)d_in[3];
  const float* gamma = (const float*)d_in[4];
  const float* beta  = (const float*)d_in[5];
  const float* W2    = (const float*)d_in[6];
  const float* b2    = (const float*)d_in[7];
  const float* t     = (const float*)d_in[8];
  float* out = (float*)d_out;

  float* ws    = (float*)d_ws;
  float* h     = ws;                              // 65536*128
  float* e     = h + (size_t)NNODE * CC;          // 65536*10
  float* p1    = e + (size_t)NNODE * 10;          // 256*128
  float* p2    = p1 + 256 * 128;                  // 256*128
  float* scale = p2 + 256 * 128;                  // 128
  float* shift = scale + CC;                      // 128

  // key(42) = (0,42); partitionable split -> k1, k2
  uint32_t k1a, k1b, k2a, k2b;
  tf2x32(0u, 42u, 0u, 0u, k1a, k1b);
  tf2x32(0u, 42u, 0u, 1u, k2a, k2b);

  k_gemm1<<<dim3(NNODE / 64), dim3(256), 0, stream>>>(x, W1, b1, h);
  k_bn_part<<<dim3(256), dim3(256), 0, stream>>>(h, p1, p2);
  k_bn_final<<<dim3(1), dim3(128), 0, stream>>>(p1, p2, gamma, beta, scale, shift);
  k_emb<<<dim3(NNODE / 64), dim3(256), 0, stream>>>(h, scale, shift, W2, b2, e, k1a, k1b);
  k_knn<<<dim3(NNODE / 8), dim3(512), 0, stream>>>(pos, out);
  k_soft<<<dim3(NNODE / 8), dim3(512), 0, stream>>>(e, t, out, k2a, k2b);
}

// Round 4
// 419.824 us; speedup vs baseline: 4.5647x; 1.0664x over previous
//
#include <hip/hip_runtime.h>
#include <stdint.h>
#include <math.h>

#define BG 64
#define NG 1024
#define KK 16
#define CC 128
#define NNODE (BG * NG)          // 65536
#define NSOFT (BG * NG * KK)     // 1048576
#define FEPS 1e-20f

__host__ __device__ __forceinline__ uint32_t rotl32u(uint32_t x, int r) {
  return (x << r) | (x >> (32 - r));
}

// Threefry-2x32, 20 rounds, exactly as jax/_src/prng.py (partitionable mode)
__host__ __device__ __forceinline__ void tf2x32(uint32_t k0, uint32_t k1,
                                                uint32_t x0, uint32_t x1,
                                                uint32_t &o0, uint32_t &o1) {
  uint32_t k2 = k0 ^ k1 ^ 0x1BD11BDAu;
  x0 += k0; x1 += k1;
#define TFR(r) { x0 += x1; x1 = rotl32u(x1, r); x1 ^= x0; }
  TFR(13) TFR(15) TFR(26) TFR(6)
  x0 += k1; x1 += k2 + 1u;
  TFR(17) TFR(29) TFR(16) TFR(24)
  x0 += k2; x1 += k0 + 2u;
  TFR(13) TFR(15) TFR(26) TFR(6)
  x0 += k0; x1 += k1 + 3u;
  TFR(17) TFR(29) TFR(16) TFR(24)
  x0 += k1; x1 += k2 + 4u;
  TFR(13) TFR(15) TFR(26) TFR(6)
  x0 += k2; x1 += k0 + 5u;
#undef TFR
  o0 = x0; o1 = x1;
}

// jax.random.uniform element m (threefry_partitionable: counter hi=0, lo=m)
__device__ __forceinline__ float jax_uniform01(uint32_t ka, uint32_t kb, uint32_t m) {
  uint32_t o0, o1;
  tf2x32(ka, kb, 0u, m, o0, o1);
  uint32_t bits = o0 ^ o1;
  float f = __uint_as_float((bits >> 9) | 0x3f800000u) - 1.0f;
  return fmaxf(f, 0.0f);
}

// Linear-quantized bin; identical computation in histogram and collect phases.
// Soft logits: v in [-49.9, 16.7]  -> LO=-50, span 67
__device__ __forceinline__ int vbin_soft(float v) {
  float fb = (v + 50.0f) * (256.0f / 67.0f);
  fb = fminf(fmaxf(fb, 0.0f), 255.0f);
  return (int)fb;
}
// KNN scores: v = -d2 in [-inf, 0] -> LO=-64, span 64 (d2>64 clamps to bin 0)
__device__ __forceinline__ int vbin_knn(float v) {
  float fb = (v + 64.0f) * 4.0f;
  fb = fminf(fmaxf(fb, 0.0f), 255.0f);
  return (int)fb;
}

#define LDS_WAIT() asm volatile("s_waitcnt lgkmcnt(0)" ::: "memory")

// ---- h = x @ W1 + b1 (+ fused per-block BN partial sums) ------------------
// p1/p2 layout: [c][1024] (column-major over blocks) for coalesced finalize.
__global__ __launch_bounds__(256) void k_gemm1(const float* __restrict__ x,
                                               const float* __restrict__ W1,
                                               const float* __restrict__ b1,
                                               float* __restrict__ h,
                                               float* __restrict__ p1,
                                               float* __restrict__ p2) {
  __shared__ __align__(16) float xs[64 * 128];   // 32 KB (reused for reduce)
  const int t = threadIdx.x;
  const size_t blockBase = (size_t)blockIdx.x * (64 * 128);
  #pragma unroll
  for (int j = 0; j < 32; ++j) xs[t + j * 256] = x[blockBase + t + j * 256];
  __syncthreads();
  const int c = t & 127;
  const int rg = t >> 7;                     // 0/1 -> rows rg*32..rg*32+31
  float acc[32];
  #pragma unroll
  for (int j = 0; j < 32; ++j) acc[j] = 0.f;
  const float* xrow = &xs[rg * 32 * 128];
  for (int k4 = 0; k4 < 128; k4 += 4) {
    const float w0 = W1[(size_t)(k4 + 0) * 128 + c];
    const float w1 = W1[(size_t)(k4 + 1) * 128 + c];
    const float w2 = W1[(size_t)(k4 + 2) * 128 + c];
    const float w3 = W1[(size_t)(k4 + 3) * 128 + c];
    #pragma unroll
    for (int j = 0; j < 32; ++j) {
      const float4 xv = *(const float4*)&xrow[j * 128 + k4];
      acc[j] = fmaf(xv.x, w0, acc[j]);
      acc[j] = fmaf(xv.y, w1, acc[j]);
      acc[j] = fmaf(xv.z, w2, acc[j]);
      acc[j] = fmaf(xv.w, w3, acc[j]);
    }
  }
  const float bb = b1[c];
  float s1 = 0.f, s2 = 0.f;
  #pragma unroll
  for (int j = 0; j < 32; ++j) {
    const float v = acc[j] + bb;
    h[blockBase + (size_t)(rg * 32 + j) * 128 + c] = v;
    s1 += v;
    s2 = fmaf(v, v, s2);
  }
  __syncthreads();                 // xs reads done; reuse as reduce buffer
  float* r1 = xs;                  // [2][128]
  float* r2 = xs + 256;            // [2][128]
  r1[rg * 128 + c] = s1;
  r2[rg * 128 + c] = s2;
  __syncthreads();
  if (t < 128) {
    p1[(size_t)t * 1024 + blockIdx.x] = r1[t] + r1[128 + t];
  } else {
    const int cc = t - 128;
    p2[(size_t)cc * 1024 + blockIdx.x] = r2[cc] + r2[128 + cc];
  }
}

// ---- finalize BN: one block per column, coalesced partial reads -----------
__global__ __launch_bounds__(256) void k_bn_final(const float* __restrict__ p1,
                                                  const float* __restrict__ p2,
                                                  const float* __restrict__ gamma,
                                                  const float* __restrict__ beta,
                                                  float* __restrict__ scale,
                                                  float* __restrict__ shift) {
  const int c = blockIdx.x, t = threadIdx.x;
  const float* q1 = p1 + (size_t)c * 1024;
  const float* q2 = p2 + (size_t)c * 1024;
  float a1 = q1[t] + q1[t + 256] + q1[t + 512] + q1[t + 768];
  float a2 = q2[t] + q2[t + 256] + q2[t + 512] + q2[t + 768];
  __shared__ float r1[256], r2[256];
  r1[t] = a1; r2[t] = a2;
  __syncthreads();
  for (int o = 128; o > 0; o >>= 1) {
    if (t < o) { r1[t] += r1[t + o]; r2[t] += r2[t + o]; }
    __syncthreads();
  }
  if (t == 0) {
    const float mu = r1[0] * (1.0f / NNODE);
    float var = r2[0] * (1.0f / NNODE) - mu * mu;
    var = fmaxf(var, 0.f);
    const float sc = gamma[c] / sqrtf(var + 1e-5f);
    scale[c] = sc;
    shift[c] = beta[c] - mu * sc;
  }
}

// ---- normalize+relu (fma) + @W2 + b2 + 0.001*uniform(k1): 64 rows/block ---
__global__ __launch_bounds__(256) void k_emb(const float* __restrict__ h,
                                             const float* __restrict__ scale,
                                             const float* __restrict__ shift,
                                             const float* __restrict__ W2,
                                             const float* __restrict__ b2,
                                             float* __restrict__ e,
                                             uint32_t ka, uint32_t kb) {
  __shared__ __align__(16) float hn[64 * 132];
  const int t = threadIdx.x;
  const int rowBase = blockIdx.x * 64;
  {
    const int c = t & 127;
    const float sc = scale[c], sh = shift[c];
    #pragma unroll
    for (int j = 0; j < 32; ++j) {
      const int r = (t >> 7) + j * 2;
      const float v = fmaf(h[(size_t)(rowBase + r) * 128 + c], sc, sh);
      hn[r * 132 + c] = fmaxf(v, 0.f);
    }
  }
  __syncthreads();
  #pragma unroll
  for (int j = 0; j < 3; ++j) {
    const int o = t + j * 256;
    if (o < 640) {
      const int r = o / 10;
      const int col = o - r * 10;
      float acc = 0.f;
      for (int k4 = 0; k4 < 128; k4 += 4) {
        const float4 hv = *(const float4*)&hn[r * 132 + k4];
        acc = fmaf(hv.x, W2[(k4 + 0) * 10 + col], acc);
        acc = fmaf(hv.y, W2[(k4 + 1) * 10 + col], acc);
        acc = fmaf(hv.z, W2[(k4 + 2) * 10 + col], acc);
        acc = fmaf(hv.w, W2[(k4 + 3) * 10 + col], acc);
      }
      acc += b2[col];
      const uint32_t m = (uint32_t)(rowBase + r) * 10u + (uint32_t)col;
      const float u = jax_uniform01(ka, kb, m);
      e[(size_t)(rowBase + r) * 10 + col] = acc + u * 0.001f;
    }
  }
}

// ---- soft edges: e-graph staged transposed in LDS; histogram select -------
__global__ __launch_bounds__(512) void k_soft(const float* __restrict__ e,
                                              const float* __restrict__ tsc,
                                              float* __restrict__ out,
                                              uint32_t ka, uint32_t kb) {
  __shared__ float    els[10 * NG];      // 40 KB, transposed: els[d*1024+s]
  __shared__ uint32_t bins[8][256];      // 8 KB, per-wave
  __shared__ float    cv[8][48];
  __shared__ int      cidx[8][48];
  __shared__ uint32_t cnt[8];
  __shared__ float    o16v[8][16];
  __shared__ int      o16i[8][16];

  const int t = threadIdx.x, lane = t & 63, w = t >> 6;
  const int node = blockIdx.x * 8 + w;
  const int b = blockIdx.x >> 7;                 // same graph for all 8 waves
  const int jt = node & (NG - 1);
  const float negt = -tsc[0];
  const float* eg = e + (size_t)b * (NG * 10);

  // zero own wave's bins + counter (per-wave state)
  { uint4 z = {0, 0, 0, 0}; *(uint4*)&bins[w][lane * 4] = z; }
  if (lane == 0) cnt[w] = 0u;

  // stage graph e transposed: write bank = s%32, lanes consecutive -> clean
  for (int s = t; s < NG; s += 512) {
    const float2* rp = (const float2*)(eg + (size_t)s * 10);
    const float2 a0 = rp[0], a1 = rp[1], a2 = rp[2], a3 = rp[3], a4 = rp[4];
    els[0 * NG + s] = a0.x; els[1 * NG + s] = a0.y;
    els[2 * NG + s] = a1.x; els[3 * NG + s] = a1.y;
    els[4 * NG + s] = a2.x; els[5 * NG + s] = a2.y;
    els[6 * NG + s] = a3.x; els[7 * NG + s] = a3.y;
    els[8 * NG + s] = a4.x; els[9 * NG + s] = a4.y;
  }
  __syncthreads();

  float ej[10];
  #pragma unroll
  for (int d = 0; d < 10; ++d) ej[d] = els[d * NG + jt];

  // phase 1: 16 scores/lane into registers, histogram into own wave's bins
  float vv[16];
  const uint32_t mL = ((uint32_t)b << 20) + (uint32_t)jt + ((uint32_t)lane << 10);
  #pragma unroll
  for (int st = 0; st < 16; ++st) {
    const int s = st * 64 + lane;
    float dd, acc;
    dd = ej[0] - els[0 * NG + s]; acc = dd * dd;
    dd = ej[1] - els[1 * NG + s]; acc = fmaf(dd, dd, acc);
    dd = ej[2] - els[2 * NG + s]; acc = fmaf(dd, dd, acc);
    dd = ej[3] - els[3 * NG + s]; acc = fmaf(dd, dd, acc);
    dd = ej[4] - els[4 * NG + s]; acc = fmaf(dd, dd, acc);
    dd = ej[5] - els[5 * NG + s]; acc = fmaf(dd, dd, acc);
    dd = ej[6] - els[6 * NG + s]; acc = fmaf(dd, dd, acc);
    dd = ej[7] - els[7 * NG + s]; acc = fmaf(dd, dd, acc);
    dd = ej[8] - els[8 * NG + s]; acc = fmaf(dd, dd, acc);
    dd = ej[9] - els[9 * NG + s]; acc = fmaf(dd, dd, acc);
    const float dist = sqrtf(acc);      // linalg.norm ...
    const float d2 = dist * dist;       // ... then **2 (match ref rounding)
    const float p = __expf(negt * d2);
    const float u = jax_uniform01(ka, kb, mL + ((uint32_t)st << 16));
    const float li = __logf(u + FEPS);
    const float g = -__logf(FEPS - li);           // gumbel
    const float v = __logf(p + FEPS) + g;
    vv[st] = v;
    atomicAdd(&bins[w][vbin_soft(v)], 1u);
  }
  LDS_WAIT();

  // phase 2: wave suffix-scan of 256 bins -> threshold bin B (= bin of v16)
  const uint4 c4 = *(const uint4*)&bins[w][lane * 4];
  const uint32_t lsum = c4.x + c4.y + c4.z + c4.w;
  uint32_t xs = lsum;
  #pragma unroll
  for (int off = 1; off < 64; off <<= 1) {
    uint32_t tt = (uint32_t)__shfl_down((int)xs, off, 64);
    if (lane + off < 64) xs += tt;
  }
  const uint32_t after = xs - lsum;
  const uint32_t s3 = c4.w + after;
  const uint32_t s2 = c4.z + s3;
  const uint32_t s1 = c4.y + s2;
  const uint32_t s0 = c4.x + s1;
  int localB = -1;
  if (s3 >= 16u) localB = lane * 4 + 3;
  else if (s2 >= 16u) localB = lane * 4 + 2;
  else if (s1 >= 16u) localB = lane * 4 + 1;
  else if (s0 >= 16u) localB = lane * 4 + 0;
  const unsigned long long msk = __ballot(localB >= 0);
  const int hl = 63 - __builtin_clzll(msk);
  const int B = __shfl(localB, hl, 64);

  // phase 3: collect candidates (bin >= B)
  #pragma unroll
  for (int st = 0; st < 16; ++st) {
    if (vbin_soft(vv[st]) >= B) {
      const uint32_t pos = atomicAdd(&cnt[w], 1u);
      if (pos < 48u) { cv[w][pos] = vv[st]; cidx[w][pos] = st * 64 + lane; }
    }
  }
  LDS_WAIT();

  // phase 4: exact rank by count with (v desc, idx asc) = jax top_k order
  int C = (int)cnt[w]; if (C > 48) C = 48;
  const float mvv = (lane < C) ? cv[w][lane] : 0.f;
  const int   mii = (lane < C) ? cidx[w][lane] : 0;
  int rank = 0;
  for (int j = 0; j < C; ++j) {
    const float vj = cv[w][j];
    const int ij = cidx[w][j];
    if (vj > mvv || (vj == mvv && ij < mii)) ++rank;
  }
  if (lane < C && rank < 16) { o16v[w][rank] = mvv; o16i[w][rank] = mii; }
  LDS_WAIT();

  // phase 5: softmax / max-normalize (literal ref op order), write outputs
  if (lane < 16) {
    const float vq = o16v[w][lane];
    const float m0 = o16v[w][0];
    float uex = __expf(vq - m0);
    float ss = uex;
    #pragma unroll
    for (int off = 1; off < 16; off <<= 1) ss += __shfl_xor(ss, off, 16);
    const float u0 = __shfl(uex, 0, 16);
    const float s0v = u0 / ss;
    const float sv = uex / ss;
    const float o = sv / s0v;
    const size_t base = (size_t)node * KK + lane;
    const float tgtf = (float)node;
    const float srcf = (float)(b * NG + o16i[w][lane]);
    out[base] = o;                                  // vals
    out[(size_t)NSOFT + base] = srcf;               // soft_idx row0
    out[2 * (size_t)NSOFT + base] = tgtf;           // soft_idx row1
    out[3 * (size_t)NSOFT + base] = srcf;           // edge row0 (soft)
    out[5 * (size_t)NSOFT + base] = tgtf;           // edge row1 (soft)
  }
}

// ---- knn edges: pos staged transposed in LDS; histogram select ------------
__global__ __launch_bounds__(512) void k_knn(const float* __restrict__ pos,
                                             float* __restrict__ out) {
  __shared__ float    pls[3 * NG];       // 12 KB transposed
  __shared__ uint32_t bins[8][256];
  __shared__ float    cv[8][48];
  __shared__ int      cidx[8][48];
  __shared__ uint32_t cnt[8];
  __shared__ int      o16i[8][16];

  const int t = threadIdx.x, lane = t & 63, w = t >> 6;
  const int node = blockIdx.x * 8 + w;
  const int b = blockIdx.x >> 7;
  const int it = node & (NG - 1);
  const float* pg = pos + (size_t)b * (NG * 3);

  { uint4 z = {0, 0, 0, 0}; *(uint4*)&bins[w][lane * 4] = z; }
  if (lane == 0) cnt[w] = 0u;

  for (int s = t; s < NG; s += 512) {
    pls[0 * NG + s] = pg[(size_t)s * 3 + 0];
    pls[1 * NG + s] = pg[(size_t)s * 3 + 1];
    pls[2 * NG + s] = pg[(size_t)s * 3 + 2];
  }
  __syncthreads();

  const float px = pls[0 * NG + it];
  const float py = pls[1 * NG + it];
  const float pz = pls[2 * NG + it];

  float vv[16];
  #pragma unroll
  for (int st = 0; st < 16; ++st) {
    const int s = st * 64 + lane;
    const float dx = px - pls[0 * NG + s];
    const float dy = py - pls[1 * NG + s];
    const float dz = pz - pls[2 * NG + s];
    float d2 = dx * dx;
    d2 = fmaf(dy, dy, d2);
    d2 = fmaf(dz, dz, d2);
    if (s == it) d2 += 1e10f;            // exclude self
    const float v = -d2;                 // top_k(-d2)
    vv[st] = v;
    atomicAdd(&bins[w][vbin_knn(v)], 1u);
  }
  LDS_WAIT();

  const uint4 c4 = *(const uint4*)&bins[w][lane * 4];
  const uint32_t lsum = c4.x + c4.y + c4.z + c4.w;
  uint32_t xs = lsum;
  #pragma unroll
  for (int off = 1; off < 64; off <<= 1) {
    uint32_t tt = (uint32_t)__shfl_down((int)xs, off, 64);
    if (lane + off < 64) xs += tt;
  }
  const uint32_t after = xs - lsum;
  const uint32_t s3 = c4.w + after;
  const uint32_t s2 = c4.z + s3;
  const uint32_t s1 = c4.y + s2;
  const uint32_t s0 = c4.x + s1;
  int localB = -1;
  if (s3 >= 16u) localB = lane * 4 + 3;
  else if (s2 >= 16u) localB = lane * 4 + 2;
  else if (s1 >= 16u) localB = lane * 4 + 1;
  else if (s0 >= 16u) localB = lane * 4 + 0;
  const unsigned long long msk = __ballot(localB >= 0);
  const int hl = 63 - __builtin_clzll(msk);
  const int B = __shfl(localB, hl, 64);

  #pragma unroll
  for (int st = 0; st < 16; ++st) {
    if (vbin_knn(vv[st]) >= B) {
      const uint32_t pos = atomicAdd(&cnt[w], 1u);
      if (pos < 48u) { cv[w][pos] = vv[st]; cidx[w][pos] = st * 64 + lane; }
    }
  }
  LDS_WAIT();

  int C = (int)cnt[w]; if (C > 48) C = 48;
  const float mvv = (lane < C) ? cv[w][lane] : 0.f;
  const int   mii = (lane < C) ? cidx[w][lane] : 0;
  int rank = 0;
  for (int j = 0; j < C; ++j) {
    const float vj = cv[w][j];
    const int ij = cidx[w][j];
    if (vj > mvv || (vj == mvv && ij < mii)) ++rank;
  }
  if (lane < C && rank < 16) o16i[w][rank] = mii;
  LDS_WAIT();

  if (lane < 16) {
    const size_t base = (size_t)node * KK + lane;
    out[4 * (size_t)NSOFT + base] = (float)(b * NG + o16i[w][lane]);  // edge row0 (knn)
    out[6 * (size_t)NSOFT + base] = (float)node;                      // edge row1 (knn)
  }
}

extern "C" void kernel_launch(void* const* d_in, const int* in_sizes, int n_in,
                              void* d_out, int out_size, void* d_ws, size_t ws_size,
                              hipStream_t stream) {
  const float* x     = (const float*)d_in[0];
  const float* pos   = (const float*)d_in[1];
  const float* W1    = (const float*)d_in[2];
  const float* b1    = (const float*)d_in[3];
  const float* gamma = (const float*)d_in[4];
  const float* beta  = (const float*)d_in[5];
  const float* W2    = (const float*)d_in[6];
  const float* b2    = (const float*)d_in[7];
  const float* t     = (const float*)d_in[8];
  float* out = (float*)d_out;

  float* ws    = (float*)d_ws;
  float* h     = ws;                              // 65536*128
  float* e     = h + (size_t)NNODE * CC;          // 65536*10
  float* p1    = e + (size_t)NNODE * 10;          // 128*1024
  float* p2    = p1 + 128 * 1024;                 // 128*1024
  float* scale = p2 + 128 * 1024;                 // 128
  float* shift = scale + CC;                      // 128

  // key(42) = (0,42); partitionable split -> k1, k2
  uint32_t k1a, k1b, k2a, k2b;
  tf2x32(0u, 42u, 0u, 0u, k1a, k1b);
  tf2x32(0u, 42u, 0u, 1u, k2a, k2b);

  k_gemm1<<<dim3(NNODE / 64), dim3(256), 0, stream>>>(x, W1, b1, h, p1, p2);
  k_bn_final<<<dim3(CC), dim3(256), 0, stream>>>(p1, p2, gamma, beta, scale, shift);
  k_emb<<<dim3(NNODE / 64), dim3(256), 0, stream>>>(h, scale, shift, W2, b2, e, k1a, k1b);
  k_knn<<<dim3(NNODE / 8), dim3(512), 0, stream>>>(pos, out);
  k_soft<<<dim3(NNODE / 8), dim3(512), 0, stream>>>(e, t, out, k2a, k2b);
}